// Round 5
// baseline (273.926 us; speedup 1.0000x reference)
//
#include <hip/hip_runtime.h>

// BondWeight: out[b, src+1, dst+1] = w; out[b, dst+1, src+1] = w (two passes,
// last-write-wins within the 1024-write per-batch sequence, numpy semantics).
// B=1024, E=512, T=8, N=256. Output 256 MB f32 -> pure HBM-write-bound.
//
// Fused strategy: per block, a u16 LDS table over a 32-row chunk holds
// packed=(seq+1)<<3|type per cell; CAS-based 16-bit max gives last-write-
// wins; stream each chunk as coalesced float4 stores, re-zeroing the table
// on the fly. LDS-only barriers (R5) keep global stores in flight across
// chunks.
//
// R8: the REAL occupancy test. R7 halved LDS (32->16 KB) expecting 32
// waves/CU, but the grid (1024 blocks / 256 CU = 4 blocks/CU) was the
// actual occupancy limiter -- LDS cap (5 blocks/CU) was never binding, so
// resident waves stayed 16/CU and the test was void. Fix: SPLIT EACH BATCH
// ACROSS 2 BLOCKS (128 rows each, 4 chunks of 32). Grid 2048 -> 8
// blocks/CU x 4 waves = 32 waves/CU, matching the 6.4 TB/s fill's
// configuration. 8 x 16 KB = 128 KB LDS/CU fits; __launch_bounds__(256,8)
// pins VGPR <= 64 for 8 waves/SIMD. Cost: each block redundantly reads all
// 512 edges (+12 MB input traffic total, trivial).
// PREDICTION: if per-CU write concurrency is the wall, dur 268 -> ~225-240.
// If neutral (266-271) on this now-valid test: kernel is at the write
// floor, residual = poison fill + fixed harness dispatch overhead ->
// declare roofline.

#define NB_E 512
#define NB_N 256
#define CH_ROWS 32
#define CHUNKS_PER_BLK 4
#define ROWS_PER_BLK (CH_ROWS * CHUNKS_PER_BLK)     // 128
#define CH_WORDS (CH_ROWS * NB_N / 2)               // 4096 u32 = 16 KB LDS
#define STREAM_IT ((CH_ROWS * NB_N / 4) / 256)      // 8 float4 per thread

typedef float v4f __attribute__((ext_vector_type(4)));

// LDS-only barrier: waits LDS ops, does NOT drain outstanding global stores.
__device__ __forceinline__ void barrier_lgkm()
{
    asm volatile("s_waitcnt lgkmcnt(0)" ::: "memory");
    __builtin_amdgcn_s_barrier();
}

__device__ __forceinline__ void lds_max_u16(unsigned int* tab, int cell, unsigned int v16)
{
    unsigned int* w = tab + (cell >> 1);
    const int sh = (cell & 1) * 16;
    unsigned int old = *w;
    while (true) {
        const unsigned int cur = (old >> sh) & 0xFFFFu;
        if (cur >= v16) break;                       // current winner is later
        const unsigned int nw = (old & ~(0xFFFFu << sh)) | (v16 << sh);
        const unsigned int seen = atomicCAS(w, old, nw);
        if (seen == old) break;
        old = seen;                                  // contended: retry
    }
}

__global__ __launch_bounds__(256, 8) void BondWeight_41738492182540_kernel(
    const float* __restrict__ weights,
    const int*   __restrict__ bsrc,
    const int*   __restrict__ bdst,
    const int*   __restrict__ btyp,
    float*       __restrict__ out)
{
    __shared__ unsigned int seqtab[CH_WORDS];
    __shared__ float s_wt[8];

    const int b     = blockIdx.x >> 1;               // batch
    const int rbase = (blockIdx.x & 1) * ROWS_PER_BLK; // 0 or 128
    const int t     = threadIdx.x;

    if (t < 8) s_wt[t] = weights[t];

    // My two edges -> four writes. seq order: pass1 (src,dst) e=0..511 then
    // pass2 (dst,src) e=0..511. packed = (seq+1)<<3 | type; max == last wins.
    // Both half-blocks of a batch compute identical pk; cells partition by
    // row, so per-cell last-write-wins is preserved.
    const int ebase = b * NB_E;
    int row[4], col[4];
    unsigned int pk[4];
    #pragma unroll
    for (int i = 0; i < 2; ++i) {
        const int e  = t + 256 * i;
        const int s1 = bsrc[ebase + e] + 1;          // [1, 255]
        const int d1 = bdst[ebase + e] + 1;
        const unsigned int ty = (unsigned int)btyp[ebase + e] & 7u;
        row[2*i]   = s1; col[2*i]   = d1; pk[2*i]   = ((unsigned int)(e + 1) << 3) | ty;
        row[2*i+1] = d1; col[2*i+1] = s1; pk[2*i+1] = ((unsigned int)(NB_E + e + 1) << 3) | ty;
    }

    // --- zero the table ONCE: 4096 u32, uint4 x 4 per thread ---
    {
        uint4* tab4 = (uint4*)seqtab;
        #pragma unroll
        for (int k = 0; k < CH_WORDS / 4 / 256; ++k)
            tab4[t + 256 * k] = make_uint4(0u, 0u, 0u, 0u);
    }
    barrier_lgkm();

    float4* __restrict__ out4 = ((float4*)out) + (size_t)b * (NB_N * NB_N / 4);
    uint2*  __restrict__ tab2 = (uint2*)seqtab;

    const int crot = blockIdx.x & (CHUNKS_PER_BLK - 1);  // chunk-order rotation
    const int krot = (blockIdx.x >> 2) & (STREAM_IT - 1);// intra-chunk start rotation

    for (int cc = 0; cc < CHUNKS_PER_BLK; ++cc) {
        const int r0 = rbase + ((cc + crot) & (CHUNKS_PER_BLK - 1)) * CH_ROWS;

        // --- scatter my writes that land in this row chunk (table is clean) ---
        #pragma unroll
        for (int i = 0; i < 4; ++i) {
            const int r = row[i] - r0;
            if (0 <= r && r < CH_ROWS)
                lds_max_u16(seqtab, r * NB_N + col[i], pk[i]);
        }
        barrier_lgkm();   // CAS results visible; prior chunk's stores stay in flight

        // --- stream chunk: 2048 float4, 8/thread, coalesced; re-zero as we go ---
        #pragma unroll
        for (int j = 0; j < STREAM_IT; ++j) {
            const int i4 = t + 256 * ((j + krot) & (STREAM_IT - 1));
            const uint2 ab = tab2[i4];               // ds_read_b64
            tab2[i4] = make_uint2(0u, 0u);           // clean for next chunk's CAS
            v4f v;
            unsigned int p;
            p = ab.x & 0xFFFFu; v.x = p ? s_wt[p & 7u] : 0.0f;
            p = ab.x >> 16;     v.y = p ? s_wt[p & 7u] : 0.0f;
            p = ab.y & 0xFFFFu; v.z = p ? s_wt[p & 7u] : 0.0f;
            p = ab.y >> 16;     v.w = p ? s_wt[p & 7u] : 0.0f;
            *(v4f*)&out4[r0 * (NB_N / 4) + i4] = v;  // store queued; never drained in-loop
        }
        barrier_lgkm();   // rezero visible before next chunk's CAS; stores in flight
    }
    // kernel end: hardware completes outstanding stores at dispatch release
}

extern "C" void kernel_launch(void* const* d_in, const int* in_sizes, int n_in,
                              void* d_out, int out_size, void* d_ws, size_t ws_size,
                              hipStream_t stream) {
    const float* weights = (const float*)d_in[0];   // [T=8]
    const int*   bsrc    = (const int*)d_in[1];     // [B, E]
    const int*   bdst    = (const int*)d_in[2];     // [B, E]
    const int*   btyp    = (const int*)d_in[3];     // [B, E]
    float*       out     = (float*)d_out;           // [B, N, N] f32

    const int nb = in_sizes[1] / NB_E;              // B = 1024

    // 2 blocks per batch (128 rows each) -> 2048 blocks -> 8 blocks/CU
    // -> 32 waves/CU, matching the rocclr fill's occupancy.
    BondWeight_41738492182540_kernel<<<nb * 2, 256, 0, stream>>>(
        weights, bsrc, bdst, btyp, out);
}